// Round 1
// baseline (332.716 us; speedup 1.0000x reference)
//
#include <hip/hip_runtime.h>
#include <hip/hip_cooperative_groups.h>

namespace cg = cooperative_groups;

#define BC 16
#define NN 2048
#define FF 128
#define DD 128
#define NEDGES 65536
#define NEG_INF -1e16f
#define LEAK 0.1f
#define CAPR 128    // per-row in-degree cap; P(Poisson(32) > 128) ~ 1e-35
#define THRS 20.0f  // defer-max threshold: exp(20)=4.9e8, fp32-safe (scale cancels at normalize)

// ---------------- helpers ----------------
__device__ __forceinline__ float dot16(const float4& a0, const float4& a1, const float4& a2, const float4& a3,
                                       const float4& v0, const float4& v1, const float4& v2, const float4& v3) {
    return a0.x * v0.x + a0.y * v0.y + a0.z * v0.z + a0.w * v0.w
         + a1.x * v1.x + a1.y * v1.y + a1.z * v1.z + a1.w * v1.w
         + a2.x * v2.x + a2.y * v2.y + a2.z * v2.z + a2.w * v2.w
         + a3.x * v3.x + a3.y * v3.y + a3.z * v3.z + a3.w * v3.w;
}
__device__ __forceinline__ void sc4(float4& c, float s) { c.x *= s; c.y *= s; c.z *= s; c.w *= s; }
__device__ __forceinline__ void fma4(float4& c, float p, const float4& v) {
    c.x += p * v.x; c.y += p * v.y; c.z += p * v.z; c.w += p * v.w;
}
__device__ __forceinline__ void add4(float4& c, const float4& v) {
    c.x += v.x; c.y += v.y; c.z += v.z; c.w += v.w;
}
__device__ __forceinline__ void red4(float4& c, int off) {
    c.x += __shfl_xor(c.x, off, 64); c.y += __shfl_xor(c.y, off, 64);
    c.z += __shfl_xor(c.z, off, 64); c.w += __shfl_xor(c.w, off, 64);
}

// ================= fused cooperative kernel =================
// phase 0: edge atomicOr (units 0..255) + zgemm 32x128 tiles (units 256..1279)
// phase 1: bitmask -> sorted CSR (shuffle prefix scan, zero atomics)
// phase 2: gat, 2 batch-slices per wave, defer-max online softmax
__global__ void __launch_bounds__(256, 4)
gat_fused(const float* __restrict__ h, const float* __restrict__ W,
          const int* __restrict__ row, const int* __restrict__ col,
          float* __restrict__ z, unsigned int* __restrict__ mask,
          unsigned short* __restrict__ hits_g, int* __restrict__ deg,
          float* __restrict__ out, int nb) {
    const int tid = threadIdx.x;
    const int blk = blockIdx.x;
    const int wv = tid >> 6, ln = tid & 63;
    cg::grid_group grid = cg::this_grid();
    __shared__ float hs[32][FF];   // 16 KB (phase 0 only)

    // ---------------- phase 0 ----------------
    for (int v = blk; v < 256 + (BC * NN) / 32; v += nb) {
        if (v < 256) {   // edge bits (mask pre-zeroed by hipMemsetAsync)
            const int e = v * 256 + tid;
            const unsigned int key = (unsigned int)row[e] * NN + (unsigned int)col[e];
            atomicOr(&mask[key >> 5], 1u << (key & 31u));
        } else {         // zgemm tile
            const size_t row0 = (size_t)(v - 256) * 32;
            const float4* hv = (const float4*)(h + row0 * FF);
            float4* hsv = (float4*)&hs[0][0];
#pragma unroll
            for (int i = 0; i < 4; ++i) hsv[tid + 256 * i] = hv[tid + 256 * i];
            __syncthreads();
            const int cc0 = (tid & 31) * 4;
            const int rr0 = (tid >> 5) * 4;
            float acc[4][4] = {};
            for (int f = 0; f < FF; f += 4) {
                float4 a[4], bb[4];
#pragma unroll
                for (int r = 0; r < 4; ++r) a[r] = *(const float4*)&hs[rr0 + r][f];
#pragma unroll
                for (int k = 0; k < 4; ++k) bb[k] = *(const float4*)&W[(f + k) * DD + cc0];
#pragma unroll
                for (int r = 0; r < 4; ++r) {
                    acc[r][0] += a[r].x * bb[0].x + a[r].y * bb[1].x + a[r].z * bb[2].x + a[r].w * bb[3].x;
                    acc[r][1] += a[r].x * bb[0].y + a[r].y * bb[1].y + a[r].z * bb[2].y + a[r].w * bb[3].y;
                    acc[r][2] += a[r].x * bb[0].z + a[r].y * bb[1].z + a[r].z * bb[2].z + a[r].w * bb[3].z;
                    acc[r][3] += a[r].x * bb[0].w + a[r].y * bb[1].w + a[r].z * bb[2].w + a[r].w * bb[3].w;
                }
            }
#pragma unroll
            for (int r = 0; r < 4; ++r)
                *(float4*)&z[(row0 + rr0 + r) * DD + cc0] =
                    make_float4(acc[r][0], acc[r][1], acc[r][2], acc[r][3]);
            __syncthreads();   // protect hs for next grid-stride unit
        }
    }
    grid.sync();

    // ---------------- phase 1: csr ----------------
    for (int v = blk; v < NN / 4; v += nb) {
        const int n = v * 4 + wv;
        unsigned int bits = mask[n * 64 + ln];
        const int cnt = __popc(bits);
        int pre = cnt;
#pragma unroll
        for (int off = 1; off <= 32; off <<= 1) {
            const int t = __shfl_up(pre, off, 64);
            if (ln >= off) pre += t;
        }
        if (ln == 63) deg[n] = pre;
        int slot = pre - cnt;
        while (bits) {
            const int bit = __ffs(bits) - 1;
            bits &= bits - 1;
            if (slot < CAPR) hits_g[n * CAPR + slot] = (unsigned short)(ln * 32 + bit);
            ++slot;
        }
    }
    grid.sync();

    // ---------------- phase 2: gat, 2 b per wave ----------------
    // task t in [0,16384): bp=(t>>2)&7 (== blk&7 when nb%8==0 -> XCD-local z slices),
    // n=((t>>5)<<2)|(t&3). Wave handles b0=2bp and b1=2bp+1 for one n.
    const int eq = ln >> 3, hq = ln & 7;
    const int doff = hq << 4;            // float offset of this lane's 16-dim chunk
    const int stride = nb << 2;
    for (int t = (blk << 2) | wv; t < 16384; t += stride) {
        const int bp = (t >> 2) & 7;
        const int n = ((t >> 5) << 2) | (t & 3);
        const float* zb0 = z + ((size_t)bp << 19);
        const float* zb1 = zb0 + (1 << 18);
        const int nh = min(deg[n], CAPR);
        const unsigned short* hrow = hits_g + n * CAPR;

        const float4* zn0 = (const float4*)(zb0 + ((size_t)n << 7) + doff);
        const float4* zn1 = (const float4*)(zb1 + ((size_t)n << 7) + doff);
        const float4 a00 = zn0[0], a01 = zn0[1], a02 = zn0[2], a03 = zn0[3];
        const float4 a10 = zn1[0], a11 = zn1[1], a12 = zn1[2], a13 = zn1[3];

        float m0 = NEG_INF, l0 = 0.f, m1 = NEG_INF, l1 = 0.f;
        float4 c00 = make_float4(0.f, 0.f, 0.f, 0.f), c01 = c00, c02 = c00, c03 = c00;
        float4 c10 = c00, c11 = c00, c12 = c00, c13 = c00;

#pragma unroll 1
        for (int e0 = 0; e0 < nh; e0 += 8) {
            const int e = e0 + eq;
            const int he = hrow[min(e, nh - 1)];   // pad lanes re-read a real edge
            const float4* p0 = (const float4*)(zb0 + ((size_t)he << 7) + doff);
            const float4* p1 = (const float4*)(zb1 + ((size_t)he << 7) + doff);
            const float4 v00 = p0[0], v01 = p0[1], v02 = p0[2], v03 = p0[3];
            const float4 v10 = p1[0], v11 = p1[1], v12 = p1[2], v13 = p1[3];

            float pt0 = dot16(a00, a01, a02, a03, v00, v01, v02, v03);
            float pt1 = dot16(a10, a11, a12, a13, v10, v11, v12, v13);
            pt0 += __shfl_xor(pt0, 1, 64);  pt1 += __shfl_xor(pt1, 1, 64);
            pt0 += __shfl_xor(pt0, 2, 64);  pt1 += __shfl_xor(pt1, 2, 64);
            pt0 += __shfl_xor(pt0, 4, 64);  pt1 += __shfl_xor(pt1, 4, 64);

            float sv0 = pt0 > 0.f ? pt0 : LEAK * pt0;   // leaky_relu(0.1)
            float sv1 = pt1 > 0.f ? pt1 : LEAK * pt1;
            const bool pad = e >= nh;
            if (sv0 == 0.f || pad) sv0 = NEG_INF;       // masked_fill(att==0) / pad
            if (sv1 == 0.f || pad) sv1 = NEG_INF;

            // defer-max: rescale only when some lane's score beats its max by >THRS
            if (__any((sv0 - m0 > THRS) | (sv1 - m1 > THRS))) {
                const float mn0 = fmaxf(m0, sv0), mn1 = fmaxf(m1, sv1);
                const float al0 = __expf(m0 - mn0), al1 = __expf(m1 - mn1);
                m0 = mn0; m1 = mn1;
                l0 *= al0; l1 *= al1;
                sc4(c00, al0); sc4(c01, al0); sc4(c02, al0); sc4(c03, al0);
                sc4(c10, al1); sc4(c11, al1); sc4(c12, al1); sc4(c13, al1);
            }
            const float pr0 = __expf(sv0 - m0), pr1 = __expf(sv1 - m1);  // exponent <= THRS
            l0 += pr0; l1 += pr1;
            fma4(c00, pr0, v00); fma4(c10, pr1, v10);
            fma4(c01, pr0, v01); fma4(c11, pr1, v11);
            fma4(c02, pr0, v02); fma4(c12, pr1, v12);
            fma4(c03, pr0, v03); fma4(c13, pr1, v13);
        }

        float M0 = m0, M1 = m1;
#pragma unroll
        for (int off = 8; off <= 32; off <<= 1) {
            M0 = fmaxf(M0, __shfl_xor(M0, off, 64));
            M1 = fmaxf(M1, __shfl_xor(M1, off, 64));
        }
        const bool ok0 = (nh > 0) && (M0 > 0.5f * NEG_INF);
        const bool ok1 = (nh > 0) && (M1 > 0.5f * NEG_INF);
        if (ok0) {   // all-pad lanes get al=exp(-1e16-M0)=0 -> garbage zeroed
            const float al = __expf(m0 - M0);
            l0 *= al; sc4(c00, al); sc4(c01, al); sc4(c02, al); sc4(c03, al);
        }
        if (ok1) {
            const float al = __expf(m1 - M1);
            l1 *= al; sc4(c10, al); sc4(c11, al); sc4(c12, al); sc4(c13, al);
        }
#pragma unroll
        for (int off = 8; off <= 32; off <<= 1) {
            l0 += __shfl_xor(l0, off, 64); l1 += __shfl_xor(l1, off, 64);
            red4(c00, off); red4(c01, off); red4(c02, off); red4(c03, off);
            red4(c10, off); red4(c11, off); red4(c12, off); red4(c13, off);
        }
        if (ok0) {
            const float inv = 1.f / l0;
            sc4(c00, inv); sc4(c01, inv); sc4(c02, inv); sc4(c03, inv);
        } else {     // no valid edge: softmax over uniform -1e16 -> mean of z[b0]
            c00 = make_float4(0.f, 0.f, 0.f, 0.f); c01 = c00; c02 = c00; c03 = c00;
            for (int mm = 0; mm < NN; ++mm) {
                const float4* zr = (const float4*)(zb0 + ((size_t)mm << 7) + doff);
                add4(c00, zr[0]); add4(c01, zr[1]); add4(c02, zr[2]); add4(c03, zr[3]);
            }
            const float s = 1.f / NN;
            sc4(c00, s); sc4(c01, s); sc4(c02, s); sc4(c03, s);
        }
        if (ok1) {
            const float inv = 1.f / l1;
            sc4(c10, inv); sc4(c11, inv); sc4(c12, inv); sc4(c13, inv);
        } else {
            c10 = make_float4(0.f, 0.f, 0.f, 0.f); c11 = c10; c12 = c10; c13 = c10;
            for (int mm = 0; mm < NN; ++mm) {
                const float4* zr = (const float4*)(zb1 + ((size_t)mm << 7) + doff);
                add4(c10, zr[0]); add4(c11, zr[1]); add4(c12, zr[2]); add4(c13, zr[3]);
            }
            const float s = 1.f / NN;
            sc4(c10, s); sc4(c11, s); sc4(c12, s); sc4(c13, s);
        }

        const int b0 = bp << 1;
        if (eq < 4) {          // lanes eq<4 store b0, eq>=4 store b1
            float4 o = c00;
            if (eq == 1) o = c01;
            if (eq == 2) o = c02;
            if (eq == 3) o = c03;
            *(float4*)(out + (((size_t)b0 * NN + n) << 7) + doff + (eq << 2)) = o;
        } else {
            float4 o = c10;
            if (eq == 5) o = c11;
            if (eq == 6) o = c12;
            if (eq == 7) o = c13;
            *(float4*)(out + (((size_t)(b0 + 1) * NN + n) << 7) + doff + ((eq - 4) << 2)) = o;
        }
    }
}

// ================= fallback path (previous verified 3-kernel pipeline) =================
__global__ void __launch_bounds__(256) zedge_kernel(const float* __restrict__ h,
                                                    const float* __restrict__ W,
                                                    float* __restrict__ z,
                                                    const int* __restrict__ row,
                                                    const int* __restrict__ col,
                                                    unsigned int* __restrict__ mask) {
    const int tid = threadIdx.x;
    const int blk = blockIdx.x;
    if (blk < 256) {
        const int e = blk * 256 + tid;
        const unsigned int key = (unsigned int)row[e] * NN + (unsigned int)col[e];
        atomicOr(&mask[key >> 5], 1u << (key & 31u));
        return;
    }
    __shared__ float hs[32][FF];
    const size_t row0 = (size_t)(blk - 256) * 32;
    const float4* hv = (const float4*)(h + row0 * FF);
    float4* hsv = (float4*)&hs[0][0];
#pragma unroll
    for (int i = 0; i < 4; ++i) hsv[tid + 256 * i] = hv[tid + 256 * i];
    __syncthreads();
    const int c0 = (tid & 31) * 4;
    const int r0 = (tid >> 5) * 4;
    float acc[4][4] = {};
    for (int f = 0; f < FF; f += 4) {
        float4 a[4], bb[4];
#pragma unroll
        for (int r = 0; r < 4; ++r) a[r] = *(const float4*)&hs[r0 + r][f];
#pragma unroll
        for (int k = 0; k < 4; ++k) bb[k] = *(const float4*)&W[(f + k) * DD + c0];
#pragma unroll
        for (int r = 0; r < 4; ++r) {
            acc[r][0] += a[r].x * bb[0].x + a[r].y * bb[1].x + a[r].z * bb[2].x + a[r].w * bb[3].x;
            acc[r][1] += a[r].x * bb[0].y + a[r].y * bb[1].y + a[r].z * bb[2].y + a[r].w * bb[3].y;
            acc[r][2] += a[r].x * bb[0].z + a[r].y * bb[1].z + a[r].z * bb[2].z + a[r].w * bb[3].z;
            acc[r][3] += a[r].x * bb[0].w + a[r].y * bb[1].w + a[r].z * bb[2].w + a[r].w * bb[3].w;
        }
    }
#pragma unroll
    for (int r = 0; r < 4; ++r)
        *(float4*)&z[(row0 + r0 + r) * DD + c0] =
            make_float4(acc[r][0], acc[r][1], acc[r][2], acc[r][3]);
}

__global__ void __launch_bounds__(256) csr_kernel(const unsigned int* __restrict__ mask,
                                                  unsigned short* __restrict__ hits_g,
                                                  int* __restrict__ deg) {
    const int tid = threadIdx.x, wv = tid >> 6, ln = tid & 63;
    const int n = blockIdx.x * 4 + wv;
    unsigned int bits = mask[n * 64 + ln];
    const int cnt = __popc(bits);
    int pre = cnt;
#pragma unroll
    for (int off = 1; off <= 32; off <<= 1) {
        const int t = __shfl_up(pre, off, 64);
        if (ln >= off) pre += t;
    }
    if (ln == 63) deg[n] = pre;
    int slot = pre - cnt;
    while (bits) {
        const int bit = __ffs(bits) - 1;
        bits &= bits - 1;
        if (slot < CAPR) hits_g[n * CAPR + slot] = (unsigned short)(ln * 32 + bit);
        ++slot;
    }
}

__global__ void __launch_bounds__(256) gat_kernel(const float* __restrict__ z,
                                                  const unsigned short* __restrict__ hits_g,
                                                  const int* __restrict__ deg,
                                                  float* __restrict__ out) {
    const int tid = threadIdx.x, wv = tid >> 6, ln = tid & 63;
    const int blk = blockIdx.x;
    const int b = ((blk & 7) << 1) | (wv & 1);
    const int n = ((blk >> 3) << 1) | (wv >> 1);
    const int eq = ln >> 3, hq = ln & 7;
    const float* zb = z + ((size_t)b << 18);
    const int nh = min(deg[n], CAPR);
    const unsigned short* hrow = hits_g + n * CAPR;
    const float4* znp = (const float4*)(zb + ((size_t)n << 7) + (hq << 4));
    const float4 a0 = znp[0], a1 = znp[1], a2 = znp[2], a3 = znp[3];
    float m = NEG_INF, l = 0.f;
    float4 acc0 = make_float4(0.f, 0.f, 0.f, 0.f), acc1 = acc0, acc2 = acc0, acc3 = acc0;
#pragma unroll 2
    for (int c0 = 0; c0 < nh; c0 += 8) {
        const int e = c0 + eq;
        const int he = hrow[min(e, nh - 1)];
        const float4* zc = (const float4*)(zb + ((size_t)he << 7) + (hq << 4));
        const float4 v0 = zc[0], v1 = zc[1], v2 = zc[2], v3 = zc[3];
        float pt = dot16(a0, a1, a2, a3, v0, v1, v2, v3);
        pt += __shfl_xor(pt, 1, 64);
        pt += __shfl_xor(pt, 2, 64);
        pt += __shfl_xor(pt, 4, 64);
        float sv = pt > 0.f ? pt : LEAK * pt;
        if (sv == 0.f || e >= nh) sv = NEG_INF;
        const float mnew = fmaxf(m, sv);
        const float alpha = __expf(m - mnew);
        const float pr = __expf(sv - mnew);
        l = l * alpha + pr;
        acc0.x = acc0.x * alpha + pr * v0.x; acc0.y = acc0.y * alpha + pr * v0.y;
        acc0.z = acc0.z * alpha + pr * v0.z; acc0.w = acc0.w * alpha + pr * v0.w;
        acc1.x = acc1.x * alpha + pr * v1.x; acc1.y = acc1.y * alpha + pr * v1.y;
        acc1.z = acc1.z * alpha + pr * v1.z; acc1.w = acc1.w * alpha + pr * v1.w;
        acc2.x = acc2.x * alpha + pr * v2.x; acc2.y = acc2.y * alpha + pr * v2.y;
        acc2.z = acc2.z * alpha + pr * v2.z; acc2.w = acc2.w * alpha + pr * v2.w;
        acc3.x = acc3.x * alpha + pr * v3.x; acc3.y = acc3.y * alpha + pr * v3.y;
        acc3.z = acc3.z * alpha + pr * v3.z; acc3.w = acc3.w * alpha + pr * v3.w;
        m = mnew;
    }
    float M = m;
#pragma unroll
    for (int off = 8; off <= 32; off <<= 1) M = fmaxf(M, __shfl_xor(M, off, 64));
    if (nh > 0 && M > 0.5f * NEG_INF) {
        const float al = __expf(m - M);
        l *= al;
        sc4(acc0, al); sc4(acc1, al); sc4(acc2, al); sc4(acc3, al);
#pragma unroll
        for (int off = 8; off <= 32; off <<= 1) {
            l += __shfl_xor(l, off, 64);
            red4(acc0, off); red4(acc1, off); red4(acc2, off); red4(acc3, off);
        }
        const float inv = 1.f / l;
        sc4(acc0, inv); sc4(acc1, inv); sc4(acc2, inv); sc4(acc3, inv);
    } else {
        acc0 = make_float4(0.f, 0.f, 0.f, 0.f); acc1 = acc0; acc2 = acc0; acc3 = acc0;
        for (int mm = 0; mm < NN; ++mm) {
            const float4* zr = (const float4*)(zb + ((size_t)mm << 7) + (hq << 4));
            add4(acc0, zr[0]); add4(acc1, zr[1]); add4(acc2, zr[2]); add4(acc3, zr[3]);
        }
        const float s = 1.f / NN;
        sc4(acc0, s); sc4(acc1, s); sc4(acc2, s); sc4(acc3, s);
    }
    if (eq < 4) {
        float4 o = acc0;
        if (eq == 1) o = acc1;
        if (eq == 2) o = acc2;
        if (eq == 3) o = acc3;
        *(float4*)(out + (((size_t)b * NN + n) << 7) + (hq << 4) + (eq << 2)) = o;
    }
}

// ---------------- launcher ----------------
extern "C" void kernel_launch(void* const* d_in, const int* in_sizes, int n_in,
                              void* d_out, int out_size, void* d_ws, size_t ws_size,
                              hipStream_t stream) {
    const float* h = (const float*)d_in[0];
    const float* W = (const float*)d_in[1];
    const int* row = (const int*)d_in[2];
    const int* col = (const int*)d_in[3];
    float* out = (float*)d_out;

    char* ws = (char*)d_ws;
    float* z = (float*)ws;                                                       // 16 MB
    unsigned int* mask = (unsigned int*)(ws + (size_t)16 * 1024 * 1024);         // 512 KB
    unsigned short* hits_g = (unsigned short*)(ws + (size_t)16 * 1024 * 1024 + 512 * 1024); // 512 KB
    int* deg = (int*)(ws + (size_t)17 * 1024 * 1024);                            // 8 KB

    static int nb = 0;
    static int coop_bad = 0;
    if (nb == 0) {
        int per_cu = 0;
        if (hipOccupancyMaxActiveBlocksPerMultiprocessor(
                &per_cu, reinterpret_cast<const void*>(gat_fused), 256, 0) != hipSuccess ||
            per_cu <= 0)
            per_cu = 4;                      // launch_bounds(256,4) guarantees this
        long g = (long)per_cu * 256;
        if (g > 2048) g = 2048;
        nb = (int)(g & ~7L);                 // multiple of 8 keeps bp == XCD id
        if (nb < 8) nb = 8;
    }

    hipMemsetAsync(mask, 0, (size_t)NN * NN / 8, stream);

    if (!coop_bad) {
        void* kargs[] = {(void*)&h, (void*)&W, (void*)&row, (void*)&col, (void*)&z,
                         (void*)&mask, (void*)&hits_g, (void*)&deg, (void*)&out, (void*)&nb};
        hipError_t err = hipLaunchCooperativeKernel(
            reinterpret_cast<const void*>(gat_fused), dim3(nb), dim3(256), kargs, 0, stream);
        if (err == hipSuccess) return;
        coop_bad = 1;                        // fall through to verified 3-kernel path
    }
    zedge_kernel<<<1280, 256, 0, stream>>>(h, W, z, row, col, mask);
    csr_kernel<<<NN / 4, 256, 0, stream>>>(mask, hits_g, deg);
    gat_kernel<<<(BC * NN) / 4, 256, 0, stream>>>(z, hits_g, deg, out);
}

// Round 4
// 150.951 us; speedup vs baseline: 2.2041x; 2.2041x over previous
//
#include <hip/hip_runtime.h>

#define BC 16
#define NN 2048
#define FF 128
#define DD 128
#define NEDGES 65536
#define NEG_INF -1e16f
#define LEAK 0.1f
#define CAPR 128   // per-row in-degree cap; P(Poisson(32) > 128) ~ 1e-35
#define THRS 20.0f // defer-max: exp(20)=4.9e8; scale cancels at normalize (numerics verified R1)

// ---------------- Kernel 1 (fused): edge atomicOr + z = h @ W ------------
// blocks 0..255: set adjacency bits (mask pre-zeroed by hipMemsetAsync).
// blocks 256..1279: register-tiled zgemm, one [32 x 128] tile of z each.
__global__ void __launch_bounds__(256) zedge_kernel(const float* __restrict__ h,
                                                    const float* __restrict__ W,
                                                    float* __restrict__ z,
                                                    const int* __restrict__ row,
                                                    const int* __restrict__ col,
                                                    unsigned int* __restrict__ mask) {
    const int tid = threadIdx.x;
    const int blk = blockIdx.x;

    if (blk < 256) {   // ---- edge part: runs first, overlaps zgemm fill
        const int e = blk * 256 + tid;
        const unsigned int key = (unsigned int)row[e] * NN + (unsigned int)col[e];
        atomicOr(&mask[key >> 5], 1u << (key & 31u));
        return;
    }

    // ---- zgemm part
    __shared__ float hs[32][FF];   // 16 KB
    const size_t row0 = (size_t)(blk - 256) * 32;
    const float4* hv = (const float4*)(h + row0 * FF);
    float4* hsv = (float4*)&hs[0][0];
#pragma unroll
    for (int i = 0; i < 4; ++i) hsv[tid + 256 * i] = hv[tid + 256 * i];
    __syncthreads();

    const int c0 = (tid & 31) * 4;
    const int r0 = (tid >> 5) * 4;
    float acc[4][4] = {};
    for (int f = 0; f < FF; f += 4) {
        float4 a[4], bb[4];
#pragma unroll
        for (int r = 0; r < 4; ++r) a[r] = *(const float4*)&hs[r0 + r][f];
#pragma unroll
        for (int k = 0; k < 4; ++k) bb[k] = *(const float4*)&W[(f + k) * DD + c0];
#pragma unroll
        for (int r = 0; r < 4; ++r) {
            acc[r][0] += a[r].x * bb[0].x + a[r].y * bb[1].x + a[r].z * bb[2].x + a[r].w * bb[3].x;
            acc[r][1] += a[r].x * bb[0].y + a[r].y * bb[1].y + a[r].z * bb[2].y + a[r].w * bb[3].y;
            acc[r][2] += a[r].x * bb[0].z + a[r].y * bb[1].z + a[r].z * bb[2].z + a[r].w * bb[3].z;
            acc[r][3] += a[r].x * bb[0].w + a[r].y * bb[1].w + a[r].z * bb[2].w + a[r].w * bb[3].w;
        }
    }
#pragma unroll
    for (int r = 0; r < 4; ++r)
        *(float4*)&z[(row0 + r0 + r) * DD + c0] =
            make_float4(acc[r][0], acc[r][1], acc[r][2], acc[r][3]);
}

// ---------------- Kernel 2: bitmask -> sorted CSR, zero atomics ----------
// one wave per row. Lane ln owns mask word ln (64 words = 2048 cols).
// Exclusive shuffle prefix-scan of popcounts gives each lane its slot base;
// bits decode in ascending column order -> gat gathers walk z[b] forward.
__global__ void __launch_bounds__(256) csr_kernel(const unsigned int* __restrict__ mask,
                                                  unsigned short* __restrict__ hits_g,
                                                  int* __restrict__ deg) {
    const int tid = threadIdx.x, wv = tid >> 6, ln = tid & 63;
    const int n = blockIdx.x * 4 + wv;
    unsigned int bits = mask[n * 64 + ln];
    const int cnt = __popc(bits);
    int pre = cnt;
#pragma unroll
    for (int off = 1; off <= 32; off <<= 1) {
        const int t = __shfl_up(pre, off, 64);
        if (ln >= off) pre += t;
    }
    if (ln == 63) deg[n] = pre;        // inclusive total (gat clamps at CAPR)
    int slot = pre - cnt;              // exclusive prefix = this lane's base
    while (bits) {
        const int bit = __ffs(bits) - 1;
        bits &= bits - 1;
        if (slot < CAPR) hits_g[n * CAPR + slot] = (unsigned short)(ln * 32 + bit);
        ++slot;
    }
}

// ---------------- Kernel 3: single-pass, lane-local online softmax -------
// R0-verified structure + defer-max: skip the 34-op rescale chain unless a
// lane's score beats its running max by >THRS (NEG_INF->real always fires,
// and its alpha=0 wipes pr=1 garbage; all-pad lanes zeroed by al=0 in the
// epilogue -- same invariants as the verified R0/R1 kernels).
__global__ void __launch_bounds__(256) gat_kernel(const float* __restrict__ z,
                                                  const unsigned short* __restrict__ hits_g,
                                                  const int* __restrict__ deg,
                                                  float* __restrict__ out) {
    const int tid = threadIdx.x, wv = tid >> 6, ln = tid & 63;
    const int blk = blockIdx.x;
    const int b = ((blk & 7) << 1) | (wv & 1);
    const int n = ((blk >> 3) << 1) | (wv >> 1);
    const int eq = ln >> 3, hq = ln & 7;

    const float* zb = z + ((size_t)b << 18);   // b*2048*128
    const int nh = min(deg[n], CAPR);
    const unsigned short* hrow = hits_g + n * CAPR;

    const float4* znp = (const float4*)(zb + ((size_t)n << 7) + (hq << 4));
    const float4 a0 = znp[0], a1 = znp[1], a2 = znp[2], a3 = znp[3];

    float m = NEG_INF, l = 0.f;
    float4 acc0 = make_float4(0.f, 0.f, 0.f, 0.f), acc1 = acc0, acc2 = acc0, acc3 = acc0;

#pragma unroll 2
    for (int c0 = 0; c0 < nh; c0 += 8) {
        const int e = c0 + eq;
        const int he = hrow[min(e, nh - 1)];     // pad lanes re-read a real edge
        const float4* zc = (const float4*)(zb + ((size_t)he << 7) + (hq << 4));
        const float4 v0 = zc[0], v1 = zc[1], v2 = zc[2], v3 = zc[3];
        float pt = a0.x * v0.x + a0.y * v0.y + a0.z * v0.z + a0.w * v0.w
                 + a1.x * v1.x + a1.y * v1.y + a1.z * v1.z + a1.w * v1.w
                 + a2.x * v2.x + a2.y * v2.y + a2.z * v2.z + a2.w * v2.w
                 + a3.x * v3.x + a3.y * v3.y + a3.z * v3.z + a3.w * v3.w;
        pt += __shfl_xor(pt, 1, 64);
        pt += __shfl_xor(pt, 2, 64);
        pt += __shfl_xor(pt, 4, 64);             // full 128-dim dot in all hq lanes
        float sv = pt > 0.f ? pt : LEAK * pt;    // leaky_relu(0.1)
        if (sv == 0.f || e >= nh) sv = NEG_INF;  // masked_fill(att==0) / pad

        if (__any(sv - m > THRS)) {              // defer-max rescale (rare)
            const float mnew = fmaxf(m, sv);
            const float alpha = __expf(m - mnew);
            m = mnew;
            l *= alpha;
            acc0.x *= alpha; acc0.y *= alpha; acc0.z *= alpha; acc0.w *= alpha;
            acc1.x *= alpha; acc1.y *= alpha; acc1.z *= alpha; acc1.w *= alpha;
            acc2.x *= alpha; acc2.y *= alpha; acc2.z *= alpha; acc2.w *= alpha;
            acc3.x *= alpha; acc3.y *= alpha; acc3.z *= alpha; acc3.w *= alpha;
        }
        const float pr = __expf(sv - m);         // exponent <= THRS, fp32-safe
        l += pr;
        acc0.x += pr * v0.x; acc0.y += pr * v0.y; acc0.z += pr * v0.z; acc0.w += pr * v0.w;
        acc1.x += pr * v1.x; acc1.y += pr * v1.y; acc1.z += pr * v1.z; acc1.w += pr * v1.w;
        acc2.x += pr * v2.x; acc2.y += pr * v2.y; acc2.z += pr * v2.z; acc2.w += pr * v2.w;
        acc3.x += pr * v3.x; acc3.y += pr * v3.y; acc3.z += pr * v3.z; acc3.w += pr * v3.w;
    }

    float M = m;
#pragma unroll
    for (int off = 8; off <= 32; off <<= 1) M = fmaxf(M, __shfl_xor(M, off, 64));

    if (nh > 0 && M > 0.5f * NEG_INF) {
        const float al = __expf(m - M);          // 0 for all-pad lanes
        l *= al;
        acc0.x *= al; acc0.y *= al; acc0.z *= al; acc0.w *= al;
        acc1.x *= al; acc1.y *= al; acc1.z *= al; acc1.w *= al;
        acc2.x *= al; acc2.y *= al; acc2.z *= al; acc2.w *= al;
        acc3.x *= al; acc3.y *= al; acc3.z *= al; acc3.w *= al;
#pragma unroll
        for (int off = 8; off <= 32; off <<= 1) {
            l += __shfl_xor(l, off, 64);
            acc0.x += __shfl_xor(acc0.x, off, 64); acc0.y += __shfl_xor(acc0.y, off, 64);
            acc0.z += __shfl_xor(acc0.z, off, 64); acc0.w += __shfl_xor(acc0.w, off, 64);
            acc1.x += __shfl_xor(acc1.x, off, 64); acc1.y += __shfl_xor(acc1.y, off, 64);
            acc1.z += __shfl_xor(acc1.z, off, 64); acc1.w += __shfl_xor(acc1.w, off, 64);
            acc2.x += __shfl_xor(acc2.x, off, 64); acc2.y += __shfl_xor(acc2.y, off, 64);
            acc2.z += __shfl_xor(acc2.z, off, 64); acc2.w += __shfl_xor(acc2.w, off, 64);
            acc3.x += __shfl_xor(acc3.x, off, 64); acc3.y += __shfl_xor(acc3.y, off, 64);
            acc3.z += __shfl_xor(acc3.z, off, 64); acc3.w += __shfl_xor(acc3.w, off, 64);
        }
        const float inv = 1.f / l;
        acc0.x *= inv; acc0.y *= inv; acc0.z *= inv; acc0.w *= inv;
        acc1.x *= inv; acc1.y *= inv; acc1.z *= inv; acc1.w *= inv;
        acc2.x *= inv; acc2.y *= inv; acc2.z *= inv; acc2.w *= inv;
        acc3.x *= inv; acc3.y *= inv; acc3.z *= inv; acc3.w *= inv;
    } else {
        // no valid edge: softmax over uniform -1e16 row -> mean of z[b]
        acc0 = make_float4(0.f, 0.f, 0.f, 0.f); acc1 = acc0; acc2 = acc0; acc3 = acc0;
        for (int mm = 0; mm < NN; ++mm) {
            const float4* zr = (const float4*)(zb + ((size_t)mm << 7) + (hq << 4));
            const float4 t0 = zr[0], t1 = zr[1], t2 = zr[2], t3 = zr[3];
            acc0.x += t0.x; acc0.y += t0.y; acc0.z += t0.z; acc0.w += t0.w;
            acc1.x += t1.x; acc1.y += t1.y; acc1.z += t1.z; acc1.w += t1.w;
            acc2.x += t2.x; acc2.y += t2.y; acc2.z += t2.z; acc2.w += t2.w;
            acc3.x += t3.x; acc3.y += t3.y; acc3.z += t3.z; acc3.w += t3.w;
        }
        const float s = 1.f / NN;
        acc0.x *= s; acc0.y *= s; acc0.z *= s; acc0.w *= s;
        acc1.x *= s; acc1.y *= s; acc1.z *= s; acc1.w *= s;
        acc2.x *= s; acc2.y *= s; acc2.z *= s; acc2.w *= s;
        acc3.x *= s; acc3.y *= s; acc3.z *= s; acc3.w *= s;
    }

    if (eq < 4) {
        float4 o = acc0;
        if (eq == 1) o = acc1;
        if (eq == 2) o = acc2;
        if (eq == 3) o = acc3;
        *(float4*)(out + (((size_t)b * NN + n) << 7) + (hq << 4) + (eq << 2)) = o;
    }
}

// ---------------- launcher ----------------
extern "C" void kernel_launch(void* const* d_in, const int* in_sizes, int n_in,
                              void* d_out, int out_size, void* d_ws, size_t ws_size,
                              hipStream_t stream) {
    const float* h = (const float*)d_in[0];
    const float* W = (const float*)d_in[1];
    const int* row = (const int*)d_in[2];
    const int* col = (const int*)d_in[3];
    float* out = (float*)d_out;

    char* ws = (char*)d_ws;
    float* z = (float*)ws;                                                     // 16 MB
    unsigned int* mask = (unsigned int*)(ws + (size_t)16 * 1024 * 1024);       // 512 KB
    unsigned short* hits_g = (unsigned short*)(ws + (size_t)16 * 1024 * 1024 + 512 * 1024); // 512 KB
    int* deg = (int*)(ws + (size_t)17 * 1024 * 1024);                          // 8 KB

    hipMemsetAsync(mask, 0, (size_t)NN * NN / 8, stream);   // DMA, ~2 us
    zedge_kernel<<<1280, 256, 0, stream>>>(h, W, z, row, col, mask);
    csr_kernel<<<NN / 4, 256, 0, stream>>>(mask, hits_g, deg);
    gat_kernel<<<(BC * NN) / 4, 256, 0, stream>>>(z, hits_g, deg, out);
}

// Round 5
// 149.715 us; speedup vs baseline: 2.2223x; 1.0083x over previous
//
#include <hip/hip_runtime.h>

#define BC 16
#define NN 2048
#define FF 128
#define DD 128
#define NEDGES 65536
#define NEG_INF -1e16f
#define LEAK 0.1f
#define CAPR 128   // per-row in-degree cap; P(Poisson(32) > 128) ~ 1e-35
#define THRS 20.0f // defer-max: exp(20)=4.9e8; scale cancels at normalize (verified R4)

// ---------------- Kernel 1 (fused): edge atomicOr + z = h @ W ------------
// blocks 0..255: set adjacency bits (mask pre-zeroed by hipMemsetAsync).
// blocks 256..1279: register-tiled zgemm, one [32 x 128] tile of z each.
__global__ void __launch_bounds__(256) zedge_kernel(const float* __restrict__ h,
                                                    const float* __restrict__ W,
                                                    float* __restrict__ z,
                                                    const int* __restrict__ row,
                                                    const int* __restrict__ col,
                                                    unsigned int* __restrict__ mask) {
    const int tid = threadIdx.x;
    const int blk = blockIdx.x;

    if (blk < 256) {   // ---- edge part: runs first, overlaps zgemm fill
        const int e = blk * 256 + tid;
        const unsigned int key = (unsigned int)row[e] * NN + (unsigned int)col[e];
        atomicOr(&mask[key >> 5], 1u << (key & 31u));
        return;
    }

    // ---- zgemm part
    __shared__ float hs[32][FF];   // 16 KB
    const size_t row0 = (size_t)(blk - 256) * 32;
    const float4* hv = (const float4*)(h + row0 * FF);
    float4* hsv = (float4*)&hs[0][0];
#pragma unroll
    for (int i = 0; i < 4; ++i) hsv[tid + 256 * i] = hv[tid + 256 * i];
    __syncthreads();

    const int c0 = (tid & 31) * 4;
    const int r0 = (tid >> 5) * 4;
    float acc[4][4] = {};
    for (int f = 0; f < FF; f += 4) {
        float4 a[4], bb[4];
#pragma unroll
        for (int r = 0; r < 4; ++r) a[r] = *(const float4*)&hs[r0 + r][f];
#pragma unroll
        for (int k = 0; k < 4; ++k) bb[k] = *(const float4*)&W[(f + k) * DD + c0];
#pragma unroll
        for (int r = 0; r < 4; ++r) {
            acc[r][0] += a[r].x * bb[0].x + a[r].y * bb[1].x + a[r].z * bb[2].x + a[r].w * bb[3].x;
            acc[r][1] += a[r].x * bb[0].y + a[r].y * bb[1].y + a[r].z * bb[2].y + a[r].w * bb[3].y;
            acc[r][2] += a[r].x * bb[0].z + a[r].y * bb[1].z + a[r].z * bb[2].z + a[r].w * bb[3].z;
            acc[r][3] += a[r].x * bb[0].w + a[r].y * bb[1].w + a[r].z * bb[2].w + a[r].w * bb[3].w;
        }
    }
#pragma unroll
    for (int r = 0; r < 4; ++r)
        *(float4*)&z[(row0 + r0 + r) * DD + c0] =
            make_float4(acc[r][0], acc[r][1], acc[r][2], acc[r][3]);
}

// ---------------- Kernel 2: bitmask -> sorted CSR, zero atomics ----------
__global__ void __launch_bounds__(256) csr_kernel(const unsigned int* __restrict__ mask,
                                                  unsigned short* __restrict__ hits_g,
                                                  int* __restrict__ deg) {
    const int tid = threadIdx.x, wv = tid >> 6, ln = tid & 63;
    const int n = blockIdx.x * 4 + wv;
    unsigned int bits = mask[n * 64 + ln];
    const int cnt = __popc(bits);
    int pre = cnt;
#pragma unroll
    for (int off = 1; off <= 32; off <<= 1) {
        const int t = __shfl_up(pre, off, 64);
        if (ln >= off) pre += t;
    }
    if (ln == 63) deg[n] = pre;        // inclusive total (gat clamps at CAPR)
    int slot = pre - cnt;              // exclusive prefix = this lane's base
    while (bits) {
        const int bit = __ffs(bits) - 1;
        bits &= bits - 1;
        if (slot < CAPR) hits_g[n * CAPR + slot] = (unsigned short)(ln * 32 + bit);
        ++slot;
    }
}

// ---------------- Kernel 3: online softmax, edge ids preloaded to regs ---
// R4-verified structure + hrow-in-registers: lane ln preloads hrow[ln] and
// hrow[64+ln] (256 B coalesced) in the prologue; each iteration's edge id
// comes from a single __shfl (register file) instead of a ~200-cycle L2
// load, so gather addresses are available immediately and loads pipeline
// across iterations. Indices past nh are uninitialized garbage -> masked
// with &(NN-1) to a valid z row; those lanes produce sv=NEG_INF anyway
// (same pad invariant as R0/R4).
__global__ void __launch_bounds__(256) gat_kernel(const float* __restrict__ z,
                                                  const unsigned short* __restrict__ hits_g,
                                                  const int* __restrict__ deg,
                                                  float* __restrict__ out) {
    const int tid = threadIdx.x, wv = tid >> 6, ln = tid & 63;
    const int blk = blockIdx.x;
    const int b = ((blk & 7) << 1) | (wv & 1);
    const int n = ((blk >> 3) << 1) | (wv >> 1);
    const int eq = ln >> 3, hq = ln & 7;

    const unsigned short* hrow = hits_g + n * CAPR;
    const int hv0 = hrow[ln];            // edges 0..63   (uninit past deg: masked later)
    const int hv1 = hrow[64 + ln];       // edges 64..127
    const int nh = min(deg[n], CAPR);

    const float* zb = z + ((size_t)b << 18);   // b*2048*128
    const float4* znp = (const float4*)(zb + ((size_t)n << 7) + (hq << 4));
    const float4 a0 = znp[0], a1 = znp[1], a2 = znp[2], a3 = znp[3];

    float m = NEG_INF, l = 0.f;
    float4 acc0 = make_float4(0.f, 0.f, 0.f, 0.f), acc1 = acc0, acc2 = acc0, acc3 = acc0;

#pragma unroll 2
    for (int c0 = 0; c0 < nh; c0 += 8) {
        const int e = c0 + eq;
        const int hv = (c0 < 64) ? hv0 : hv1;      // uniform select (c0 is loop-scalar)
        const int he = __shfl(hv, e & 63, 64) & (NN - 1);   // edge id from registers
        const float4* zc = (const float4*)(zb + ((size_t)he << 7) + (hq << 4));
        const float4 v0 = zc[0], v1 = zc[1], v2 = zc[2], v3 = zc[3];
        // two independent 8-FMA chains halve the serial dot depth
        float ch0 = a0.x * v0.x + a0.y * v0.y + a0.z * v0.z + a0.w * v0.w
                  + a1.x * v1.x + a1.y * v1.y + a1.z * v1.z + a1.w * v1.w;
        float ch1 = a2.x * v2.x + a2.y * v2.y + a2.z * v2.z + a2.w * v2.w
                  + a3.x * v3.x + a3.y * v3.y + a3.z * v3.z + a3.w * v3.w;
        float pt = ch0 + ch1;
        pt += __shfl_xor(pt, 1, 64);
        pt += __shfl_xor(pt, 2, 64);
        pt += __shfl_xor(pt, 4, 64);             // full 128-dim dot in all hq lanes
        float sv = pt > 0.f ? pt : LEAK * pt;    // leaky_relu(0.1)
        if (sv == 0.f || e >= nh) sv = NEG_INF;  // masked_fill(att==0) / pad

        if (__any(sv - m > THRS)) {              // defer-max rescale (rare)
            const float mnew = fmaxf(m, sv);
            const float alpha = __expf(m - mnew);
            m = mnew;
            l *= alpha;
            acc0.x *= alpha; acc0.y *= alpha; acc0.z *= alpha; acc0.w *= alpha;
            acc1.x *= alpha; acc1.y *= alpha; acc1.z *= alpha; acc1.w *= alpha;
            acc2.x *= alpha; acc2.y *= alpha; acc2.z *= alpha; acc2.w *= alpha;
            acc3.x *= alpha; acc3.y *= alpha; acc3.z *= alpha; acc3.w *= alpha;
        }
        const float pr = __expf(sv - m);         // exponent <= THRS, fp32-safe
        l += pr;
        acc0.x += pr * v0.x; acc0.y += pr * v0.y; acc0.z += pr * v0.z; acc0.w += pr * v0.w;
        acc1.x += pr * v1.x; acc1.y += pr * v1.y; acc1.z += pr * v1.z; acc1.w += pr * v1.w;
        acc2.x += pr * v2.x; acc2.y += pr * v2.y; acc2.z += pr * v2.z; acc2.w += pr * v2.w;
        acc3.x += pr * v3.x; acc3.y += pr * v3.y; acc3.z += pr * v3.z; acc3.w += pr * v3.w;
    }

    float M = m;
#pragma unroll
    for (int off = 8; off <= 32; off <<= 1) M = fmaxf(M, __shfl_xor(M, off, 64));

    if (nh > 0 && M > 0.5f * NEG_INF) {
        const float al = __expf(m - M);          // 0 for all-pad lanes
        l *= al;
        acc0.x *= al; acc0.y *= al; acc0.z *= al; acc0.w *= al;
        acc1.x *= al; acc1.y *= al; acc1.z *= al; acc1.w *= al;
        acc2.x *= al; acc2.y *= al; acc2.z *= al; acc2.w *= al;
        acc3.x *= al; acc3.y *= al; acc3.z *= al; acc3.w *= al;
#pragma unroll
        for (int off = 8; off <= 32; off <<= 1) {
            l += __shfl_xor(l, off, 64);
            acc0.x += __shfl_xor(acc0.x, off, 64); acc0.y += __shfl_xor(acc0.y, off, 64);
            acc0.z += __shfl_xor(acc0.z, off, 64); acc0.w += __shfl_xor(acc0.w, off, 64);
            acc1.x += __shfl_xor(acc1.x, off, 64); acc1.y += __shfl_xor(acc1.y, off, 64);
            acc1.z += __shfl_xor(acc1.z, off, 64); acc1.w += __shfl_xor(acc1.w, off, 64);
            acc2.x += __shfl_xor(acc2.x, off, 64); acc2.y += __shfl_xor(acc2.y, off, 64);
            acc2.z += __shfl_xor(acc2.z, off, 64); acc2.w += __shfl_xor(acc2.w, off, 64);
            acc3.x += __shfl_xor(acc3.x, off, 64); acc3.y += __shfl_xor(acc3.y, off, 64);
            acc3.z += __shfl_xor(acc3.z, off, 64); acc3.w += __shfl_xor(acc3.w, off, 64);
        }
        const float inv = 1.f / l;
        acc0.x *= inv; acc0.y *= inv; acc0.z *= inv; acc0.w *= inv;
        acc1.x *= inv; acc1.y *= inv; acc1.z *= inv; acc1.w *= inv;
        acc2.x *= inv; acc2.y *= inv; acc2.z *= inv; acc2.w *= inv;
        acc3.x *= inv; acc3.y *= inv; acc3.z *= inv; acc3.w *= inv;
    } else {
        // no valid edge: softmax over uniform -1e16 row -> mean of z[b]
        acc0 = make_float4(0.f, 0.f, 0.f, 0.f); acc1 = acc0; acc2 = acc0; acc3 = acc0;
        for (int mm = 0; mm < NN; ++mm) {
            const float4* zr = (const float4*)(zb + ((size_t)mm << 7) + (hq << 4));
            const float4 t0 = zr[0], t1 = zr[1], t2 = zr[2], t3 = zr[3];
            acc0.x += t0.x; acc0.y += t0.y; acc0.z += t0.z; acc0.w += t0.w;
            acc1.x += t1.x; acc1.y += t1.y; acc1.z += t1.z; acc1.w += t1.w;
            acc2.x += t2.x; acc2.y += t2.y; acc2.z += t2.z; acc2.w += t2.w;
            acc3.x += t3.x; acc3.y += t3.y; acc3.z += t3.z; acc3.w += t3.w;
        }
        const float s = 1.f / NN;
        acc0.x *= s; acc0.y *= s; acc0.z *= s; acc0.w *= s;
        acc1.x *= s; acc1.y *= s; acc1.z *= s; acc1.w *= s;
        acc2.x *= s; acc2.y *= s; acc2.z *= s; acc2.w *= s;
        acc3.x *= s; acc3.y *= s; acc3.z *= s; acc3.w *= s;
    }

    if (eq < 4) {
        float4 o = acc0;
        if (eq == 1) o = acc1;
        if (eq == 2) o = acc2;
        if (eq == 3) o = acc3;
        *(float4*)(out + (((size_t)b * NN + n) << 7) + (hq << 4) + (eq << 2)) = o;
    }
}

// ---------------- launcher ----------------
extern "C" void kernel_launch(void* const* d_in, const int* in_sizes, int n_in,
                              void* d_out, int out_size, void* d_ws, size_t ws_size,
                              hipStream_t stream) {
    const float* h = (const float*)d_in[0];
    const float* W = (const float*)d_in[1];
    const int* row = (const int*)d_in[2];
    const int* col = (const int*)d_in[3];
    float* out = (float*)d_out;

    char* ws = (char*)d_ws;
    float* z = (float*)ws;                                                     // 16 MB
    unsigned int* mask = (unsigned int*)(ws + (size_t)16 * 1024 * 1024);       // 512 KB
    unsigned short* hits_g = (unsigned short*)(ws + (size_t)16 * 1024 * 1024 + 512 * 1024); // 512 KB
    int* deg = (int*)(ws + (size_t)17 * 1024 * 1024);                          // 8 KB

    hipMemsetAsync(mask, 0, (size_t)NN * NN / 8, stream);   // DMA, ~2 us
    zedge_kernel<<<1280, 256, 0, stream>>>(h, W, z, row, col, mask);
    csr_kernel<<<NN / 4, 256, 0, stream>>>(mask, hits_g, deg);
    gat_kernel<<<(BC * NN) / 4, 256, 0, stream>>>(z, hits_g, deg, out);
}

// Round 6
// 147.800 us; speedup vs baseline: 2.2511x; 1.0130x over previous
//
#include <hip/hip_runtime.h>

#define BC 16
#define NN 2048
#define FF 128
#define DD 128
#define NEDGES 65536
#define NEG_INF -1e16f
#define LEAK 0.1f
#define CAPR 128   // per-row in-degree cap; P(Poisson(32) > 128) ~ 1e-35
#define THRS 20.0f // defer-max: exp(20)=4.9e8; scale cancels at normalize (verified R4/R5)

// ---------------- Kernel 1 (fused): edge atomicOr + z = h @ W ------------
// blocks 0..255: set adjacency bits (mask pre-zeroed by hipMemsetAsync).
// blocks 256..1279: register-tiled zgemm, one [32 x 128] tile of z each.
// (byte-identical to the R5-verified kernel)
__global__ void __launch_bounds__(256) zedge_kernel(const float* __restrict__ h,
                                                    const float* __restrict__ W,
                                                    float* __restrict__ z,
                                                    const int* __restrict__ row,
                                                    const int* __restrict__ col,
                                                    unsigned int* __restrict__ mask) {
    const int tid = threadIdx.x;
    const int blk = blockIdx.x;

    if (blk < 256) {   // ---- edge part: runs first, overlaps zgemm fill
        const int e = blk * 256 + tid;
        const unsigned int key = (unsigned int)row[e] * NN + (unsigned int)col[e];
        atomicOr(&mask[key >> 5], 1u << (key & 31u));
        return;
    }

    // ---- zgemm part
    __shared__ float hs[32][FF];   // 16 KB
    const size_t row0 = (size_t)(blk - 256) * 32;
    const float4* hv = (const float4*)(h + row0 * FF);
    float4* hsv = (float4*)&hs[0][0];
#pragma unroll
    for (int i = 0; i < 4; ++i) hsv[tid + 256 * i] = hv[tid + 256 * i];
    __syncthreads();

    const int c0 = (tid & 31) * 4;
    const int r0 = (tid >> 5) * 4;
    float acc[4][4] = {};
    for (int f = 0; f < FF; f += 4) {
        float4 a[4], bb[4];
#pragma unroll
        for (int r = 0; r < 4; ++r) a[r] = *(const float4*)&hs[r0 + r][f];
#pragma unroll
        for (int k = 0; k < 4; ++k) bb[k] = *(const float4*)&W[(f + k) * DD + c0];
#pragma unroll
        for (int r = 0; r < 4; ++r) {
            acc[r][0] += a[r].x * bb[0].x + a[r].y * bb[1].x + a[r].z * bb[2].x + a[r].w * bb[3].x;
            acc[r][1] += a[r].x * bb[0].y + a[r].y * bb[1].y + a[r].z * bb[2].y + a[r].w * bb[3].y;
            acc[r][2] += a[r].x * bb[0].z + a[r].y * bb[1].z + a[r].z * bb[2].z + a[r].w * bb[3].z;
            acc[r][3] += a[r].x * bb[0].w + a[r].y * bb[1].w + a[r].z * bb[2].w + a[r].w * bb[3].w;
        }
    }
#pragma unroll
    for (int r = 0; r < 4; ++r)
        *(float4*)&z[(row0 + r0 + r) * DD + c0] =
            make_float4(acc[r][0], acc[r][1], acc[r][2], acc[r][3]);
}

// ---------------- Kernel 2: gat with fused in-wave CSR decode ------------
// one wave per (b, n). Prologue: lane ln owns mask word ln of row n (256 B
// coalesced); shuffle prefix-scan of popcounts gives slot bases; bits decode
// in ascending column order into a 1 KB wave-private LDS list (replaces the
// csr_kernel dispatch). Edge ids then preload into 2 regs per lane and are
// fetched per-iteration by a single __shfl (R5-verified pattern).
// Loop/epilogue byte-identical to the R5-verified kernel.
__global__ void __launch_bounds__(256) gat_kernel(const float* __restrict__ z,
                                                  const unsigned int* __restrict__ mask,
                                                  float* __restrict__ out) {
    __shared__ unsigned short hits_l[4][CAPR];   // 1 KB, one row per wave
    const int tid = threadIdx.x, wv = tid >> 6, ln = tid & 63;
    const int blk = blockIdx.x;
    const int b = ((blk & 7) << 1) | (wv & 1);
    const int n = ((blk >> 3) << 1) | (wv >> 1);
    const int eq = ln >> 3, hq = ln & 7;

    // ---- in-wave CSR decode (wave-private LDS; same-wave DS ordering)
    unsigned int bits = mask[n * 64 + ln];
    const int cnt = __popc(bits);
    int pre = cnt;
#pragma unroll
    for (int off = 1; off <= 32; off <<= 1) {
        const int t = __shfl_up(pre, off, 64);
        if (ln >= off) pre += t;
    }
    const int total = __shfl(pre, 63, 64);   // inclusive total = row degree
    int slot = pre - cnt;                    // exclusive prefix = lane's base
    while (bits) {
        const int bit = __ffs(bits) - 1;
        bits &= bits - 1;
        if (slot < CAPR) hits_l[wv][slot] = (unsigned short)(ln * 32 + bit);
        ++slot;
    }
    const int nh = min(total, CAPR);
    // preload edge list to registers (slots >= total are uninit: masked below)
    const int hv0 = hits_l[wv][ln];          // edges 0..63
    const int hv1 = hits_l[wv][64 + ln];     // edges 64..127

    const float* zb = z + ((size_t)b << 18);   // b*2048*128
    const float4* znp = (const float4*)(zb + ((size_t)n << 7) + (hq << 4));
    const float4 a0 = znp[0], a1 = znp[1], a2 = znp[2], a3 = znp[3];

    float m = NEG_INF, l = 0.f;
    float4 acc0 = make_float4(0.f, 0.f, 0.f, 0.f), acc1 = acc0, acc2 = acc0, acc3 = acc0;

#pragma unroll 2
    for (int c0 = 0; c0 < nh; c0 += 8) {
        const int e = c0 + eq;
        const int hv = (c0 < 64) ? hv0 : hv1;      // uniform select (c0 loop-scalar)
        const int he = __shfl(hv, e & 63, 64) & (NN - 1);   // edge id from registers
        const float4* zc = (const float4*)(zb + ((size_t)he << 7) + (hq << 4));
        const float4 v0 = zc[0], v1 = zc[1], v2 = zc[2], v3 = zc[3];
        // two independent 8-FMA chains halve the serial dot depth
        float ch0 = a0.x * v0.x + a0.y * v0.y + a0.z * v0.z + a0.w * v0.w
                  + a1.x * v1.x + a1.y * v1.y + a1.z * v1.z + a1.w * v1.w;
        float ch1 = a2.x * v2.x + a2.y * v2.y + a2.z * v2.z + a2.w * v2.w
                  + a3.x * v3.x + a3.y * v3.y + a3.z * v3.z + a3.w * v3.w;
        float pt = ch0 + ch1;
        pt += __shfl_xor(pt, 1, 64);
        pt += __shfl_xor(pt, 2, 64);
        pt += __shfl_xor(pt, 4, 64);             // full 128-dim dot in all hq lanes
        float sv = pt > 0.f ? pt : LEAK * pt;    // leaky_relu(0.1)
        if (sv == 0.f || e >= nh) sv = NEG_INF;  // masked_fill(att==0) / pad

        if (__any(sv - m > THRS)) {              // defer-max rescale (rare)
            const float mnew = fmaxf(m, sv);
            const float alpha = __expf(m - mnew);
            m = mnew;
            l *= alpha;
            acc0.x *= alpha; acc0.y *= alpha; acc0.z *= alpha; acc0.w *= alpha;
            acc1.x *= alpha; acc1.y *= alpha; acc1.z *= alpha; acc1.w *= alpha;
            acc2.x *= alpha; acc2.y *= alpha; acc2.z *= alpha; acc2.w *= alpha;
            acc3.x *= alpha; acc3.y *= alpha; acc3.z *= alpha; acc3.w *= alpha;
        }
        const float pr = __expf(sv - m);         // exponent <= THRS, fp32-safe
        l += pr;
        acc0.x += pr * v0.x; acc0.y += pr * v0.y; acc0.z += pr * v0.z; acc0.w += pr * v0.w;
        acc1.x += pr * v1.x; acc1.y += pr * v1.y; acc1.z += pr * v1.z; acc1.w += pr * v1.w;
        acc2.x += pr * v2.x; acc2.y += pr * v2.y; acc2.z += pr * v2.z; acc2.w += pr * v2.w;
        acc3.x += pr * v3.x; acc3.y += pr * v3.y; acc3.z += pr * v3.z; acc3.w += pr * v3.w;
    }

    float M = m;
#pragma unroll
    for (int off = 8; off <= 32; off <<= 1) M = fmaxf(M, __shfl_xor(M, off, 64));

    if (nh > 0 && M > 0.5f * NEG_INF) {
        const float al = __expf(m - M);          // 0 for all-pad lanes
        l *= al;
        acc0.x *= al; acc0.y *= al; acc0.z *= al; acc0.w *= al;
        acc1.x *= al; acc1.y *= al; acc1.z *= al; acc1.w *= al;
        acc2.x *= al; acc2.y *= al; acc2.z *= al; acc2.w *= al;
        acc3.x *= al; acc3.y *= al; acc3.z *= al; acc3.w *= al;
#pragma unroll
        for (int off = 8; off <= 32; off <<= 1) {
            l += __shfl_xor(l, off, 64);
            acc0.x += __shfl_xor(acc0.x, off, 64); acc0.y += __shfl_xor(acc0.y, off, 64);
            acc0.z += __shfl_xor(acc0.z, off, 64); acc0.w += __shfl_xor(acc0.w, off, 64);
            acc1.x += __shfl_xor(acc1.x, off, 64); acc1.y += __shfl_xor(acc1.y, off, 64);
            acc1.z += __shfl_xor(acc1.z, off, 64); acc1.w += __shfl_xor(acc1.w, off, 64);
            acc2.x += __shfl_xor(acc2.x, off, 64); acc2.y += __shfl_xor(acc2.y, off, 64);
            acc2.z += __shfl_xor(acc2.z, off, 64); acc2.w += __shfl_xor(acc2.w, off, 64);
            acc3.x += __shfl_xor(acc3.x, off, 64); acc3.y += __shfl_xor(acc3.y, off, 64);
            acc3.z += __shfl_xor(acc3.z, off, 64); acc3.w += __shfl_xor(acc3.w, off, 64);
        }
        const float inv = 1.f / l;
        acc0.x *= inv; acc0.y *= inv; acc0.z *= inv; acc0.w *= inv;
        acc1.x *= inv; acc1.y *= inv; acc1.z *= inv; acc1.w *= inv;
        acc2.x *= inv; acc2.y *= inv; acc2.z *= inv; acc2.w *= inv;
        acc3.x *= inv; acc3.y *= inv; acc3.z *= inv; acc3.w *= inv;
    } else {
        // no valid edge: softmax over uniform -1e16 row -> mean of z[b]
        acc0 = make_float4(0.f, 0.f, 0.f, 0.f); acc1 = acc0; acc2 = acc0; acc3 = acc0;
        for (int mm = 0; mm < NN; ++mm) {
            const float4* zr = (const float4*)(zb + ((size_t)mm << 7) + (hq << 4));
            const float4 t0 = zr[0], t1 = zr[1], t2 = zr[2], t3 = zr[3];
            acc0.x += t0.x; acc0.y += t0.y; acc0.z += t0.z; acc0.w += t0.w;
            acc1.x += t1.x; acc1.y += t1.y; acc1.z += t1.z; acc1.w += t1.w;
            acc2.x += t2.x; acc2.y += t2.y; acc2.z += t2.z; acc2.w += t2.w;
            acc3.x += t3.x; acc3.y += t3.y; acc3.z += t3.z; acc3.w += t3.w;
        }
        const float s = 1.f / NN;
        acc0.x *= s; acc0.y *= s; acc0.z *= s; acc0.w *= s;
        acc1.x *= s; acc1.y *= s; acc1.z *= s; acc1.w *= s;
        acc2.x *= s; acc2.y *= s; acc2.z *= s; acc2.w *= s;
        acc3.x *= s; acc3.y *= s; acc3.z *= s; acc3.w *= s;
    }

    if (eq < 4) {
        float4 o = acc0;
        if (eq == 1) o = acc1;
        if (eq == 2) o = acc2;
        if (eq == 3) o = acc3;
        *(float4*)(out + (((size_t)b * NN + n) << 7) + (hq << 4) + (eq << 2)) = o;
    }
}

// ---------------- launcher ----------------
extern "C" void kernel_launch(void* const* d_in, const int* in_sizes, int n_in,
                              void* d_out, int out_size, void* d_ws, size_t ws_size,
                              hipStream_t stream) {
    const float* h = (const float*)d_in[0];
    const float* W = (const float*)d_in[1];
    const int* row = (const int*)d_in[2];
    const int* col = (const int*)d_in[3];
    float* out = (float*)d_out;

    char* ws = (char*)d_ws;
    float* z = (float*)ws;                                                 // 16 MB
    unsigned int* mask = (unsigned int*)(ws + (size_t)16 * 1024 * 1024);   // 512 KB

    hipMemsetAsync(mask, 0, (size_t)NN * NN / 8, stream);   // DMA, ~2 us
    zedge_kernel<<<1280, 256, 0, stream>>>(h, W, z, row, col, mask);
    gat_kernel<<<(BC * NN) / 4, 256, 0, stream>>>(z, mask, out);
}